// Round 11
// baseline (245.644 us; speedup 1.0000x reference)
//
#include <hip/hip_runtime.h>
#include <hip/hip_fp16.h>

#define D 128
#define PCH 4096   // edges per partition block

typedef _Float16 half_t;
typedef _Float16 f16x8 __attribute__((ext_vector_type(8)));
typedef _Float16 f16x4 __attribute__((ext_vector_type(4)));
typedef float    f32x4 __attribute__((ext_vector_type(4)));

// ================= hist (blocks 0..511) + W->fp16 conversion (blocks 512..543) =================
__global__ __launch_bounds__(256) void k_histw(const int* __restrict__ dstv, int* bcnt,
                                               int e, int nb,
                                               const float* __restrict__ W1,
                                               const float* __restrict__ W2,
                                               half_t* __restrict__ Wh) {
    if (blockIdx.x >= 512) {
        int q = (blockIdx.x - 512) * 256 + threadIdx.x;   // 0..8191
        if (q < 8192) {
            const float4* src = (q < 4096) ? (const float4*)W1 : (const float4*)W2;
            float4 v = src[q & 4095];
            f16x4 h;
            h[0] = (_Float16)v.x; h[1] = (_Float16)v.y;
            h[2] = (_Float16)v.z; h[3] = (_Float16)v.w;
            ((f16x4*)Wh)[q] = h;
        }
        return;
    }
    __shared__ int h[512];
    for (int i = threadIdx.x; i < nb; i += 256) h[i] = 0;
    __syncthreads();
    const int stride = 512 * 256;
    for (int i = blockIdx.x * 256 + threadIdx.x; i < e; i += stride)
        atomicAdd(&h[dstv[i] >> 8], 1);
    __syncthreads();
    for (int i = threadIdx.x; i < nb; i += 256)
        if (h[i]) atomicAdd(&bcnt[i], h[i]);
}

// partition edges into bucket-contiguous ebuf, packed (src<<8)|(dst&255)
// bbase recomputed in-LDS (exclusive scan of bcnt); bcur is a zero-init'd relative cursor
__global__ __launch_bounds__(512) void k_part(const int* __restrict__ srcv,
                                              const int* __restrict__ dstv,
                                              const int* __restrict__ bcnt,
                                              int* bcur, unsigned int* __restrict__ ebuf,
                                              int e, int nb) {
    __shared__ int sd[512];
    __shared__ int bexcl[512];
    __shared__ int h[512];
    __shared__ int base[512];
    int t = threadIdx.x;
    // ---- in-LDS exclusive scan of bcnt ----
    int v = (t < nb) ? bcnt[t] : 0;
    sd[t] = v;
    __syncthreads();
    for (int o = 1; o < 512; o <<= 1) {
        int x = (t >= o) ? sd[t - o] : 0;
        __syncthreads();
        sd[t] += x;
        __syncthreads();
    }
    bexcl[t] = sd[t] - v;
    for (int i = t; i < nb; i += 512) h[i] = 0;
    __syncthreads();

    int c0 = blockIdx.x * PCH;
    int c1 = min(c0 + PCH, e);
    for (int i = c0 + t; i < c1; i += 512)
        atomicAdd(&h[dstv[i] >> 8], 1);
    __syncthreads();
    for (int i = t; i < nb; i += 512) {
        int c = h[i];
        base[i] = c ? (bexcl[i] + atomicAdd(&bcur[i], c)) : 0;
    }
    __syncthreads();
    for (int i = t; i < nb; i += 512) h[i] = 0;
    __syncthreads();
    for (int i = c0 + t; i < c1; i += 512) {
        int d = dstv[i];
        int b = d >> 8;
        int pos = atomicAdd(&h[b], 1);
        ebuf[base[b] + pos] = ((unsigned int)srcv[i] << 8) | (unsigned int)(d & 255);
    }
}

// per-bucket: local count -> rowptr + dis, then fill csr_src (contiguous slice)
// bucket bounds recomputed in-LDS from bcnt
__global__ __launch_bounds__(512) void k_bucket(const unsigned int* __restrict__ ebuf,
                                                const int* __restrict__ bcnt,
                                                int* __restrict__ rowptr,
                                                int* __restrict__ csr_src,
                                                float* __restrict__ dis, int n, int e,
                                                int nb) {
    __shared__ int sd[512];
    __shared__ int cnt[256];
    __shared__ int off[256];
    int b = blockIdx.x;
    int t = threadIdx.x;
    // ---- in-LDS inclusive scan of bcnt -> bucket bounds ----
    int v0 = (t < nb) ? bcnt[t] : 0;
    sd[t] = v0;
    __syncthreads();
    for (int o = 1; o < 512; o <<= 1) {
        int x = (t >= o) ? sd[t - o] : 0;
        __syncthreads();
        sd[t] += x;
        __syncthreads();
    }
    int s1 = sd[b];                       // inclusive
    int s0 = s1 - ((b < nb) ? bcnt[b] : 0);
    __syncthreads();

    if (t < 256) cnt[t] = 0;
    __syncthreads();
    for (int i = s0 + t; i < s1; i += 512)
        atomicAdd(&cnt[ebuf[i] & 255], 1);
    __syncthreads();
    int v = (t < 256) ? cnt[t] : 0;
    if (t < 256) off[t] = v;
    __syncthreads();
    for (int o = 1; o < 256; o <<= 1) {
        int x = (t >= o && t < 256) ? off[t - o] : 0;
        __syncthreads();
        if (t < 256) off[t] += x;
        __syncthreads();
    }
    if (t < 256) {
        int excl = off[t] - v;
        int node = b * 256 + t;
        if (node < n) {
            rowptr[node] = s0 + excl;
            dis[node] = rsqrtf((float)(v + 1));   // +1 self loop
        }
        if (b == 0 && t == 0) rowptr[n] = e;
        cnt[t] = excl;   // reuse as local cursor
    }
    __syncthreads();
    for (int i = s0 + t; i < s1; i += 512) {
        unsigned int u = ebuf[i];
        int pos = atomicAdd(&cnt[u & 255], 1);
        csr_src[s0 + pos] = (int)(u >> 8);
    }
}

// ================= MFMA GEMM: G = (X @ W^T + b) * dis[row], fp32 in / fp16 out =================
__global__ __launch_bounds__(512) void k_gemm(const float* __restrict__ Xv,
                                              const half_t* __restrict__ Wh,
                                              const float* __restrict__ B,
                                              const float* __restrict__ dis,
                                              half_t* __restrict__ Gh, int n) {
    __shared__ _Float16 lds[128 * 136];
    const int t = threadIdx.x;
    const int row0 = blockIdx.x * 128;

    #pragma unroll
    for (int i = 0; i < 4; ++i) {
        int gid = i * 512 + t;          // 2048 granules = 128 rows x 16
        int row = gid >> 4, g = gid & 15;
        int grow = row0 + row;
        int so = ((g ^ (row & 7)) * 8);
        float4 a = make_float4(0.f, 0.f, 0.f, 0.f);
        float4 b = make_float4(0.f, 0.f, 0.f, 0.f);
        if (grow < n) {
            a = ((const float4*)Xv)[(size_t)grow * 32 + g * 2];
            b = ((const float4*)Xv)[(size_t)grow * 32 + g * 2 + 1];
        }
        f16x8 hv;
        hv[0] = (_Float16)a.x; hv[1] = (_Float16)a.y;
        hv[2] = (_Float16)a.z; hv[3] = (_Float16)a.w;
        hv[4] = (_Float16)b.x; hv[5] = (_Float16)b.y;
        hv[6] = (_Float16)b.z; hv[7] = (_Float16)b.w;
        *(f16x8*)&lds[row * 128 + so] = hv;
    }
    __syncthreads();

    const int w = t >> 6, l = t & 63;
    const int rbase = (w >> 1) * 32;
    const int cbase = (w & 1) * 64;
    const int lr = l & 15, lk = l >> 4;

    f32x4 acc[2][4] = {};

    #pragma unroll
    for (int kb = 0; kb < 4; ++kb) {
        f16x8 bf[4], af[2];
        #pragma unroll
        for (int ct = 0; ct < 4; ++ct) {
            int j = cbase + ct * 16 + lr;
            bf[ct] = *(const f16x8*)(Wh + j * 128 + kb * 32 + lk * 8);
        }
        #pragma unroll
        for (int rt = 0; rt < 2; ++rt) {
            int row = rbase + rt * 16 + lr;
            int G = kb * 4 + lk;
            af[rt] = *(const f16x8*)&lds[row * 128 + ((G ^ (row & 7)) * 8)];
        }
        #pragma unroll
        for (int rt = 0; rt < 2; ++rt)
            #pragma unroll
            for (int ct = 0; ct < 4; ++ct)
                acc[rt][ct] = __builtin_amdgcn_mfma_f32_16x16x32_f16(af[rt], bf[ct],
                                                                    acc[rt][ct], 0, 0, 0);
    }

    float bc[4];
    #pragma unroll
    for (int ct = 0; ct < 4; ++ct) bc[ct] = B[cbase + ct * 16 + lr];

    __syncthreads();
    #pragma unroll
    for (int rt = 0; rt < 2; ++rt)
        #pragma unroll
        for (int q = 0; q < 4; ++q) {
            int rl = rbase + rt * 16 + lk * 4 + q;
            int grow = row0 + rl;
            float ds = (grow < n) ? dis[grow] : 0.f;
            #pragma unroll
            for (int ct = 0; ct < 4; ++ct) {
                float v = (acc[rt][ct][q] + bc[ct]) * ds;
                lds[rl * 136 + cbase + ct * 16 + lr] = (_Float16)v;
            }
        }
    __syncthreads();
    #pragma unroll
    for (int i = 0; i < 4; ++i) {
        int gid = i * 512 + t;
        int row = gid >> 4, g = gid & 15;
        int grow = row0 + row;
        if (grow < n)
            *(f16x8*)&Gh[(size_t)grow * 128 + g * 8] = *(f16x8*)&lds[row * 136 + g * 8];
    }
}

// ================= FUSED: gather1 (G1 -> h1 in LDS) + GEMM2 (h1 @ W2^T) =================
// Per 128-row tile: 32 groups x 16 lanes gather/PReLU rows into swizzled LDS A-tile,
// then the MFMA phase computes G2 = (h1 @ W2^T + b2) * dis, stored fp16 coalesced.
__global__ __launch_bounds__(512) void k_fusedg(const half_t* __restrict__ G1,
                                                const float* __restrict__ dis,
                                                const int* __restrict__ rowptr,
                                                const int* __restrict__ csr_src,
                                                const float* __restrict__ a,
                                                const half_t* __restrict__ Wh,
                                                const float* __restrict__ B,
                                                half_t* __restrict__ G2, int n) {
    __shared__ _Float16 lds[128 * 136];
    const int t = threadIdx.x;
    const int row0 = blockIdx.x * 128;
    const int grp = t >> 4;        // 0..31
    const int sl  = t & 15;        // column octet
    const float al = a[0];
    const uint4* Gv = (const uint4*)G1;

    #pragma unroll 1
    for (int it = 0; it < 4; ++it) {
        int rl = it * 32 + grp;
        int node = row0 + rl;
        float ac[8];
        #pragma unroll
        for (int j = 0; j < 8; ++j) ac[j] = 0.f;
        if (node < n) {
            uint4 su = Gv[(size_t)node * 16 + sl];
            f16x8 h = *(f16x8*)&su;
            #pragma unroll
            for (int j = 0; j < 8; ++j) ac[j] = (float)h[j];
            int e = rowptr[node], e1 = rowptr[node + 1];
            for (; e + 4 <= e1; e += 4) {
                int s0 = csr_src[e + 0];
                int s1 = csr_src[e + 1];
                int s2 = csr_src[e + 2];
                int s3 = csr_src[e + 3];
                uint4 u0 = Gv[(size_t)s0 * 16 + sl];
                uint4 u1 = Gv[(size_t)s1 * 16 + sl];
                uint4 u2 = Gv[(size_t)s2 * 16 + sl];
                uint4 u3 = Gv[(size_t)s3 * 16 + sl];
                f16x8 h0 = *(f16x8*)&u0;
                f16x8 h1 = *(f16x8*)&u1;
                f16x8 h2 = *(f16x8*)&u2;
                f16x8 h3 = *(f16x8*)&u3;
                #pragma unroll
                for (int j = 0; j < 8; ++j)
                    ac[j] += (float)h0[j] + (float)h1[j] + (float)h2[j] + (float)h3[j];
            }
            for (; e < e1; ++e) {
                int s = csr_src[e];
                uint4 u = Gv[(size_t)s * 16 + sl];
                f16x8 h = *(f16x8*)&u;
                #pragma unroll
                for (int j = 0; j < 8; ++j) ac[j] += (float)h[j];
            }
            float dsc = dis[node];
            #pragma unroll
            for (int j = 0; j < 8; ++j) {
                float v = ac[j] * dsc;
                ac[j] = v > 0.f ? v : al * v;
            }
        }
        f16x8 hv;
        #pragma unroll
        for (int j = 0; j < 8; ++j) hv[j] = (_Float16)ac[j];
        *(f16x8*)&lds[rl * 128 + ((sl ^ (rl & 7)) * 8)] = hv;
    }
    __syncthreads();

    // ---- MFMA phase (identical to k_gemm compute/epilogue) ----
    const int w = t >> 6, l = t & 63;
    const int rbase = (w >> 1) * 32;
    const int cbase = (w & 1) * 64;
    const int lr = l & 15, lk = l >> 4;

    f32x4 acc[2][4] = {};

    #pragma unroll
    for (int kb = 0; kb < 4; ++kb) {
        f16x8 bf[4], af[2];
        #pragma unroll
        for (int ct = 0; ct < 4; ++ct) {
            int j = cbase + ct * 16 + lr;
            bf[ct] = *(const f16x8*)(Wh + j * 128 + kb * 32 + lk * 8);
        }
        #pragma unroll
        for (int rt = 0; rt < 2; ++rt) {
            int row = rbase + rt * 16 + lr;
            int G = kb * 4 + lk;
            af[rt] = *(const f16x8*)&lds[row * 128 + ((G ^ (row & 7)) * 8)];
        }
        #pragma unroll
        for (int rt = 0; rt < 2; ++rt)
            #pragma unroll
            for (int ct = 0; ct < 4; ++ct)
                acc[rt][ct] = __builtin_amdgcn_mfma_f32_16x16x32_f16(af[rt], bf[ct],
                                                                    acc[rt][ct], 0, 0, 0);
    }

    float bc[4];
    #pragma unroll
    for (int ct = 0; ct < 4; ++ct) bc[ct] = B[cbase + ct * 16 + lr];

    __syncthreads();
    #pragma unroll
    for (int rt = 0; rt < 2; ++rt)
        #pragma unroll
        for (int q = 0; q < 4; ++q) {
            int rl = rbase + rt * 16 + lk * 4 + q;
            int grow = row0 + rl;
            float ds = (grow < n) ? dis[grow] : 0.f;
            #pragma unroll
            for (int ct = 0; ct < 4; ++ct) {
                float v = (acc[rt][ct][q] + bc[ct]) * ds;
                lds[rl * 136 + cbase + ct * 16 + lr] = (_Float16)v;
            }
        }
    __syncthreads();
    #pragma unroll
    for (int i = 0; i < 4; ++i) {
        int gid = i * 512 + t;
        int row = gid >> 4, g = gid & 15;
        int grow = row0 + row;
        if (grow < n)
            *(f16x8*)&G2[(size_t)grow * 128 + g * 8] = *(f16x8*)&lds[row * 136 + g * 8];
    }
}

// ================= gather-aggregate + self loop + PReLU (final layer, fp32 out) =================
__global__ __launch_bounds__(256) void k_gather(const half_t* __restrict__ G,
                                                const float* __restrict__ dis,
                                                const int* __restrict__ rowptr,
                                                const int* __restrict__ csr_src,
                                                const float* __restrict__ a,
                                                float* __restrict__ O, int n, int nquad) {
    int wq = (blockIdx.x * 256 + threadIdx.x) >> 6;
    if (wq >= nquad) return;
    int lane = threadIdx.x & 63;
    int node = wq * 4 + (lane >> 4);
    if (node >= n) node = n - 1;   // duplicate last node (identical writes)
    int sl = lane & 15;            // column octet 0..15

    const uint4* Gv = (const uint4*)G;
    float ac[8];
    {
        uint4 su = Gv[(size_t)node * 16 + sl];
        f16x8 h = *(f16x8*)&su;
        #pragma unroll
        for (int j = 0; j < 8; ++j) ac[j] = (float)h[j];
    }

    int e = rowptr[node], e1 = rowptr[node + 1];
    for (; e + 4 <= e1; e += 4) {
        int s0 = csr_src[e + 0];
        int s1 = csr_src[e + 1];
        int s2 = csr_src[e + 2];
        int s3 = csr_src[e + 3];
        uint4 u0 = Gv[(size_t)s0 * 16 + sl];
        uint4 u1 = Gv[(size_t)s1 * 16 + sl];
        uint4 u2 = Gv[(size_t)s2 * 16 + sl];
        uint4 u3 = Gv[(size_t)s3 * 16 + sl];
        f16x8 h0 = *(f16x8*)&u0;
        f16x8 h1 = *(f16x8*)&u1;
        f16x8 h2 = *(f16x8*)&u2;
        f16x8 h3 = *(f16x8*)&u3;
        #pragma unroll
        for (int j = 0; j < 8; ++j)
            ac[j] += (float)h0[j] + (float)h1[j] + (float)h2[j] + (float)h3[j];
    }
    for (; e < e1; ++e) {
        int s = csr_src[e];
        uint4 u = Gv[(size_t)s * 16 + sl];
        f16x8 h = *(f16x8*)&u;
        #pragma unroll
        for (int j = 0; j < 8; ++j) ac[j] += (float)h[j];
    }

    float dsc = dis[node];
    float al = a[0];
    #pragma unroll
    for (int j = 0; j < 8; ++j) {
        float v = ac[j] * dsc;
        ac[j] = v > 0.f ? v : al * v;
    }
    float4 o0 = make_float4(ac[0], ac[1], ac[2], ac[3]);
    float4 o1 = make_float4(ac[4], ac[5], ac[6], ac[7]);
    ((float4*)O)[(size_t)node * 32 + sl * 2]     = o0;
    ((float4*)O)[(size_t)node * 32 + sl * 2 + 1] = o1;
}

extern "C" void kernel_launch(void* const* d_in, const int* in_sizes, int n_in,
                              void* d_out, int out_size, void* d_ws, size_t ws_size,
                              hipStream_t stream) {
    const float* x  = (const float*)d_in[0];
    const int*   ei = (const int*)d_in[1];
    const float* W1 = (const float*)d_in[2];
    const float* b1 = (const float*)d_in[3];
    const float* a1 = (const float*)d_in[4];
    const float* W2 = (const float*)d_in[5];
    const float* b2 = (const float*)d_in[6];
    const float* a2 = (const float*)d_in[7];

    const int n = in_sizes[0] / D;
    const int e = in_sizes[1] / 2;
    const int* srcv = ei;
    const int* dstv = ei + e;
    const int nb = (n + 255) >> 8;   // buckets of 256 nodes (nb <= 512)

    char* ws = (char*)d_ws;
    size_t off = 0;
    auto alloc = [&](size_t bytes) {
        void* p = ws + off;
        off = (off + bytes + 255) & ~(size_t)255;
        return p;
    };
    float*        dis     = (float*)       alloc((size_t)n * 4);
    int*          rowptr  = (int*)         alloc((size_t)(n + 1) * 4);
    int*          csr_src = (int*)         alloc((size_t)e * 4);
    int*          bcnt    = (int*)         alloc(1024 * 4);   // [0:512) counts, [512:1024) cursors
    unsigned int* ebuf    = (unsigned int*)alloc((size_t)e * 4);
    half_t*       bufA    = (half_t*)      alloc((size_t)n * D * 2);   // G1 (fp16)
    half_t*       bufB    = (half_t*)      alloc((size_t)n * D * 2);   // G2 (fp16)
    half_t*       Wh      = (half_t*)      alloc(2 * 16384 * 2);       // W1,W2 fp16
    int*          bcur    = bcnt + 512;

    dim3 blk(256);
    const int npart = (e + PCH - 1) / PCH;

    hipMemsetAsync(bcnt, 0, 1024 * 4, stream);
    k_histw <<<544, blk, 0, stream>>>(dstv, bcnt, e, nb, W1, W2, Wh);
    k_part  <<<npart, 512, 0, stream>>>(srcv, dstv, bcnt, bcur, ebuf, e, nb);
    k_bucket<<<nb, 512, 0, stream>>>(ebuf, bcnt, rowptr, csr_src, dis, n, e, nb);

    const int nquad = (n + 3) / 4;
    const int gat_grid = (nquad * 64 + 255) / 256;
    const int gemm_grid = (n + 127) / 128;

    // layer 1 GEMM: x(fp32) -> G1(fp16)
    k_gemm  <<<gemm_grid, 512, 0, stream>>>(x, Wh, b1, dis, bufA, n);
    // fused: gather1(G1) -> h1 in LDS -> GEMM2 -> G2(fp16)
    k_fusedg<<<gemm_grid, 512, 0, stream>>>(bufA, dis, rowptr, csr_src, a1,
                                            Wh + 16384, b2, bufB, n);
    // final gather: G2 -> out(fp32)
    k_gather<<<gat_grid, blk, 0, stream>>>(bufB, dis, rowptr, csr_src, a2,
                                           (float*)d_out, n, nquad);
}

// Round 12
// 237.728 us; speedup vs baseline: 1.0333x; 1.0333x over previous
//
#include <hip/hip_runtime.h>
#include <hip/hip_fp16.h>

#define D 128
#define PCH 4096   // edges per partition block

typedef _Float16 half_t;
typedef _Float16 f16x8 __attribute__((ext_vector_type(8)));
typedef _Float16 f16x4 __attribute__((ext_vector_type(4)));
typedef float    f32x4 __attribute__((ext_vector_type(4)));

// ================= hist (blocks 0..511) + W->fp16 conversion (blocks 512..543) =================
__global__ __launch_bounds__(256) void k_histw(const int* __restrict__ dstv, int* bcnt,
                                               int e, int nb,
                                               const float* __restrict__ W1,
                                               const float* __restrict__ W2,
                                               half_t* __restrict__ Wh) {
    if (blockIdx.x >= 512) {
        int q = (blockIdx.x - 512) * 256 + threadIdx.x;   // 0..8191
        if (q < 8192) {
            const float4* src = (q < 4096) ? (const float4*)W1 : (const float4*)W2;
            float4 v = src[q & 4095];
            f16x4 h;
            h[0] = (_Float16)v.x; h[1] = (_Float16)v.y;
            h[2] = (_Float16)v.z; h[3] = (_Float16)v.w;
            ((f16x4*)Wh)[q] = h;
        }
        return;
    }
    __shared__ int h[512];
    for (int i = threadIdx.x; i < nb; i += 256) h[i] = 0;
    __syncthreads();
    const int stride = 512 * 256;
    for (int i = blockIdx.x * 256 + threadIdx.x; i < e; i += stride)
        atomicAdd(&h[dstv[i] >> 8], 1);
    __syncthreads();
    for (int i = threadIdx.x; i < nb; i += 256)
        if (h[i]) atomicAdd(&bcnt[i], h[i]);
}

// partition edges into bucket-contiguous ebuf, packed (src<<8)|(dst&255)
// bucket bases recomputed in-LDS (exclusive scan of bcnt); bcur = zero-init relative cursor
__global__ __launch_bounds__(512) void k_part(const int* __restrict__ srcv,
                                              const int* __restrict__ dstv,
                                              const int* __restrict__ bcnt,
                                              int* bcur, unsigned int* __restrict__ ebuf,
                                              int e, int nb) {
    __shared__ int sd[512];
    __shared__ int bexcl[512];
    __shared__ int h[512];
    __shared__ int base[512];
    int t = threadIdx.x;
    int v = (t < nb) ? bcnt[t] : 0;
    sd[t] = v;
    __syncthreads();
    for (int o = 1; o < 512; o <<= 1) {
        int x = (t >= o) ? sd[t - o] : 0;
        __syncthreads();
        sd[t] += x;
        __syncthreads();
    }
    bexcl[t] = sd[t] - v;
    for (int i = t; i < nb; i += 512) h[i] = 0;
    __syncthreads();

    int c0 = blockIdx.x * PCH;
    int c1 = min(c0 + PCH, e);
    for (int i = c0 + t; i < c1; i += 512)
        atomicAdd(&h[dstv[i] >> 8], 1);
    __syncthreads();
    for (int i = t; i < nb; i += 512) {
        int c = h[i];
        base[i] = c ? (bexcl[i] + atomicAdd(&bcur[i], c)) : 0;
    }
    __syncthreads();
    for (int i = t; i < nb; i += 512) h[i] = 0;
    __syncthreads();
    for (int i = c0 + t; i < c1; i += 512) {
        int d = dstv[i];
        int b = d >> 8;
        int pos = atomicAdd(&h[b], 1);
        ebuf[base[b] + pos] = ((unsigned int)srcv[i] << 8) | (unsigned int)(d & 255);
    }
}

// per-bucket: local count -> rowptr + dis, then fill csr_src (contiguous slice)
__global__ __launch_bounds__(512) void k_bucket(const unsigned int* __restrict__ ebuf,
                                                const int* __restrict__ bcnt,
                                                int* __restrict__ rowptr,
                                                int* __restrict__ csr_src,
                                                float* __restrict__ dis, int n, int e,
                                                int nb) {
    __shared__ int sd[512];
    __shared__ int cnt[256];
    __shared__ int off[256];
    int b = blockIdx.x;
    int t = threadIdx.x;
    int v0 = (t < nb) ? bcnt[t] : 0;
    sd[t] = v0;
    __syncthreads();
    for (int o = 1; o < 512; o <<= 1) {
        int x = (t >= o) ? sd[t - o] : 0;
        __syncthreads();
        sd[t] += x;
        __syncthreads();
    }
    int s1 = sd[b];                       // inclusive
    int s0 = s1 - ((b < nb) ? bcnt[b] : 0);
    __syncthreads();

    if (t < 256) cnt[t] = 0;
    __syncthreads();
    for (int i = s0 + t; i < s1; i += 512)
        atomicAdd(&cnt[ebuf[i] & 255], 1);
    __syncthreads();
    int v = (t < 256) ? cnt[t] : 0;
    if (t < 256) off[t] = v;
    __syncthreads();
    for (int o = 1; o < 256; o <<= 1) {
        int x = (t >= o && t < 256) ? off[t - o] : 0;
        __syncthreads();
        if (t < 256) off[t] += x;
        __syncthreads();
    }
    if (t < 256) {
        int excl = off[t] - v;
        int node = b * 256 + t;
        if (node < n) {
            rowptr[node] = s0 + excl;
            dis[node] = rsqrtf((float)(v + 1));   // +1 self loop
        }
        if (b == 0 && t == 0) rowptr[n] = e;
        cnt[t] = excl;   // reuse as local cursor
    }
    __syncthreads();
    for (int i = s0 + t; i < s1; i += 512) {
        unsigned int u = ebuf[i];
        int pos = atomicAdd(&cnt[u & 255], 1);
        csr_src[s0 + pos] = (int)(u >> 8);
    }
}

// ================= MFMA GEMM: G = (X @ W^T + b) * dis[row], fp16 out =================
// block 512 thr = 8 waves; tile 128x128; wave -> 32 rows x 64 cols.
// A staged fp16 in LDS (XOR-swizzled 16B granules); B (Wh) from global (L2-hot).
// Epilogue repacks through LDS for coalesced f16x8 stores.
template<bool FP16IN>
__global__ __launch_bounds__(512) void k_gemm(const void* __restrict__ Xv,
                                              const half_t* __restrict__ Wh,
                                              const float* __restrict__ B,
                                              const float* __restrict__ dis,
                                              half_t* __restrict__ Gh, int n) {
    __shared__ _Float16 lds[128 * 136];
    const int t = threadIdx.x;
    const int row0 = blockIdx.x * 128;

    #pragma unroll
    for (int i = 0; i < 4; ++i) {
        int gid = i * 512 + t;          // 2048 granules = 128 rows x 16
        int row = gid >> 4, g = gid & 15;
        int grow = row0 + row;
        int so = ((g ^ (row & 7)) * 8);
        f16x8 hv;
        if constexpr (FP16IN) {
            uint4 u = make_uint4(0, 0, 0, 0);
            if (grow < n) u = ((const uint4*)Xv)[(size_t)grow * 16 + g];
            hv = *(f16x8*)&u;
        } else {
            float4 a = make_float4(0.f, 0.f, 0.f, 0.f);
            float4 b = make_float4(0.f, 0.f, 0.f, 0.f);
            if (grow < n) {
                a = ((const float4*)Xv)[(size_t)grow * 32 + g * 2];
                b = ((const float4*)Xv)[(size_t)grow * 32 + g * 2 + 1];
            }
            hv[0] = (_Float16)a.x; hv[1] = (_Float16)a.y;
            hv[2] = (_Float16)a.z; hv[3] = (_Float16)a.w;
            hv[4] = (_Float16)b.x; hv[5] = (_Float16)b.y;
            hv[6] = (_Float16)b.z; hv[7] = (_Float16)b.w;
        }
        *(f16x8*)&lds[row * 128 + so] = hv;
    }
    __syncthreads();

    const int w = t >> 6, l = t & 63;
    const int rbase = (w >> 1) * 32;
    const int cbase = (w & 1) * 64;
    const int lr = l & 15, lk = l >> 4;

    f32x4 acc[2][4] = {};

    #pragma unroll
    for (int kb = 0; kb < 4; ++kb) {
        f16x8 bf[4], af[2];
        #pragma unroll
        for (int ct = 0; ct < 4; ++ct) {
            int j = cbase + ct * 16 + lr;
            bf[ct] = *(const f16x8*)(Wh + j * 128 + kb * 32 + lk * 8);
        }
        #pragma unroll
        for (int rt = 0; rt < 2; ++rt) {
            int row = rbase + rt * 16 + lr;
            int G = kb * 4 + lk;
            af[rt] = *(const f16x8*)&lds[row * 128 + ((G ^ (row & 7)) * 8)];
        }
        #pragma unroll
        for (int rt = 0; rt < 2; ++rt)
            #pragma unroll
            for (int ct = 0; ct < 4; ++ct)
                acc[rt][ct] = __builtin_amdgcn_mfma_f32_16x16x32_f16(af[rt], bf[ct],
                                                                    acc[rt][ct], 0, 0, 0);
    }

    float bc[4];
    #pragma unroll
    for (int ct = 0; ct < 4; ++ct) bc[ct] = B[cbase + ct * 16 + lr];

    __syncthreads();
    #pragma unroll
    for (int rt = 0; rt < 2; ++rt)
        #pragma unroll
        for (int q = 0; q < 4; ++q) {
            int rl = rbase + rt * 16 + lk * 4 + q;
            int grow = row0 + rl;
            float ds = (grow < n) ? dis[grow] : 0.f;
            #pragma unroll
            for (int ct = 0; ct < 4; ++ct) {
                float v = (acc[rt][ct][q] + bc[ct]) * ds;
                lds[rl * 136 + cbase + ct * 16 + lr] = (_Float16)v;
            }
        }
    __syncthreads();
    #pragma unroll
    for (int i = 0; i < 4; ++i) {
        int gid = i * 512 + t;
        int row = gid >> 4, g = gid & 15;
        int grow = row0 + row;
        if (grow < n)
            *(f16x8*)&Gh[(size_t)grow * 128 + g * 8] = *(f16x8*)&lds[row * 136 + g * 8];
    }
}

// ================= gather-aggregate + self loop + PReLU =================
// FOUR nodes per wave: 16 lanes per node; lane owns 8 cols (uint4 = 16 B).
template<bool FP16OUT>
__global__ __launch_bounds__(256) void k_gather(const half_t* __restrict__ G,
                                                const float* __restrict__ dis,
                                                const int* __restrict__ rowptr,
                                                const int* __restrict__ csr_src,
                                                const float* __restrict__ a,
                                                void* __restrict__ O, int n, int nquad) {
    int wq = (blockIdx.x * 256 + threadIdx.x) >> 6;
    if (wq >= nquad) return;
    int lane = threadIdx.x & 63;
    int node = wq * 4 + (lane >> 4);
    if (node >= n) node = n - 1;   // duplicate last node (identical writes)
    int sl = lane & 15;            // column octet 0..15

    const uint4* Gv = (const uint4*)G;   // one uint4 = 8 halves
    float ac[8];
    {
        uint4 su = Gv[(size_t)node * 16 + sl];
        f16x8 h = *(f16x8*)&su;
        #pragma unroll
        for (int j = 0; j < 8; ++j) ac[j] = (float)h[j];
    }

    int e = rowptr[node], e1 = rowptr[node + 1];
    for (; e + 4 <= e1; e += 4) {
        int s0 = csr_src[e + 0];
        int s1 = csr_src[e + 1];
        int s2 = csr_src[e + 2];
        int s3 = csr_src[e + 3];
        uint4 u0 = Gv[(size_t)s0 * 16 + sl];
        uint4 u1 = Gv[(size_t)s1 * 16 + sl];
        uint4 u2 = Gv[(size_t)s2 * 16 + sl];
        uint4 u3 = Gv[(size_t)s3 * 16 + sl];
        f16x8 h0 = *(f16x8*)&u0;
        f16x8 h1 = *(f16x8*)&u1;
        f16x8 h2 = *(f16x8*)&u2;
        f16x8 h3 = *(f16x8*)&u3;
        #pragma unroll
        for (int j = 0; j < 8; ++j)
            ac[j] += (float)h0[j] + (float)h1[j] + (float)h2[j] + (float)h3[j];
    }
    for (; e < e1; ++e) {
        int s = csr_src[e];
        uint4 u = Gv[(size_t)s * 16 + sl];
        f16x8 h = *(f16x8*)&u;
        #pragma unroll
        for (int j = 0; j < 8; ++j) ac[j] += (float)h[j];
    }

    float dsc = dis[node];
    float al = a[0];
    #pragma unroll
    for (int j = 0; j < 8; ++j) {
        float v = ac[j] * dsc;
        ac[j] = v > 0.f ? v : al * v;
    }
    if constexpr (FP16OUT) {
        f16x8 h;
        #pragma unroll
        for (int j = 0; j < 8; ++j) h[j] = (_Float16)ac[j];
        ((f16x8*)O)[(size_t)node * 16 + sl] = h;
    } else {
        float4 o0 = make_float4(ac[0], ac[1], ac[2], ac[3]);
        float4 o1 = make_float4(ac[4], ac[5], ac[6], ac[7]);
        ((float4*)O)[(size_t)node * 32 + sl * 2]     = o0;
        ((float4*)O)[(size_t)node * 32 + sl * 2 + 1] = o1;
    }
}

extern "C" void kernel_launch(void* const* d_in, const int* in_sizes, int n_in,
                              void* d_out, int out_size, void* d_ws, size_t ws_size,
                              hipStream_t stream) {
    const float* x  = (const float*)d_in[0];
    const int*   ei = (const int*)d_in[1];
    const float* W1 = (const float*)d_in[2];
    const float* b1 = (const float*)d_in[3];
    const float* a1 = (const float*)d_in[4];
    const float* W2 = (const float*)d_in[5];
    const float* b2 = (const float*)d_in[6];
    const float* a2 = (const float*)d_in[7];

    const int n = in_sizes[0] / D;
    const int e = in_sizes[1] / 2;
    const int* srcv = ei;
    const int* dstv = ei + e;
    const int nb = (n + 255) >> 8;   // buckets of 256 nodes (nb <= 512)

    char* ws = (char*)d_ws;
    size_t off = 0;
    auto alloc = [&](size_t bytes) {
        void* p = ws + off;
        off = (off + bytes + 255) & ~(size_t)255;
        return p;
    };
    float*        dis     = (float*)       alloc((size_t)n * 4);
    int*          rowptr  = (int*)         alloc((size_t)(n + 1) * 4);
    int*          csr_src = (int*)         alloc((size_t)e * 4);
    int*          bcnt    = (int*)         alloc(1024 * 4);   // [0:512) counts, [512:1024) cursors
    unsigned int* ebuf    = (unsigned int*)alloc((size_t)e * 4);
    half_t*       bufA    = (half_t*)      alloc((size_t)n * D * 2);   // G (fp16)
    half_t*       h1h     = (half_t*)      alloc((size_t)n * D * 2);   // h1 (fp16)
    half_t*       Wh      = (half_t*)      alloc(2 * 16384 * 2);       // W1,W2 fp16
    int*          bcur    = bcnt + 512;

    dim3 blk(256);
    const int npart = (e + PCH - 1) / PCH;

    hipMemsetAsync(bcnt, 0, 1024 * 4, stream);
    k_histw <<<544, blk, 0, stream>>>(dstv, bcnt, e, nb, W1, W2, Wh);
    k_part  <<<npart, 512, 0, stream>>>(srcv, dstv, bcnt, bcur, ebuf, e, nb);
    k_bucket<<<nb, 512, 0, stream>>>(ebuf, bcnt, rowptr, csr_src, dis, n, e, nb);

    const int nquad = (n + 3) / 4;
    const int gat_grid = (nquad * 64 + 255) / 256;
    const int gemm_grid = (n + 127) / 128;

    // layer 1: x(fp32) -> G1(bufA fp16) -> h1(fp16)
    k_gemm<false><<<gemm_grid, 512, 0, stream>>>(x, Wh, b1, dis, bufA, n);
    k_gather<true><<<gat_grid, blk, 0, stream>>>(bufA, dis, rowptr, csr_src, a1, h1h, n, nquad);
    // layer 2: h1(fp16) -> G2(bufA fp16) -> out(fp32)
    k_gemm<true><<<gemm_grid, 512, 0, stream>>>(h1h, Wh + 16384, b2, dis, bufA, n);
    k_gather<false><<<gat_grid, blk, 0, stream>>>(bufA, dis, rowptr, csr_src, a2, d_out, n, nquad);
}